// Round 14
// baseline (532.793 us; speedup 1.0000x reference)
//
#include <hip/hip_runtime.h>
#include <math.h>

// Problem constants (reference: H, W, D = 96, 80, 128; KS=1 -> 27 offsets)
#define HH 96
#define WW 80
#define DD 128
#define SLICE (WW * DD)       // 10240
#define NVOX (HH * WW * DD)   // 983040

struct W4d { double w0, w1, w2, w3; };
struct Raw { float4 t[3]; float4 s[3]; };

__device__ __forceinline__ float4 zf4() { return make_float4(0.f, 0.f, 0.f, 0.f); }

// f64 2D 9-tap combine of one slice (3 rows x 6 cols incl. shfl halo) into
// P = w0*c + w1*f + w2*e and Q = w1*c + w2*f + w3*e (d^2 weight classes).
// out3d(z) = P(z) + Q(z-1) + Q(z+1), rounded once to f32 => correctly-rounded
// conv up to ~1e-16 f64 reassociation.
__device__ __forceinline__ void pq_rows(const float4 rows[3], int q, const W4d& w,
                                        double P[4], double Q[4]) {
  double d[3][6];
  #pragma unroll
  for (int r = 0; r < 3; ++r) {
    float4 v = rows[r];
    float l = __shfl_up(v.w, 1);
    float rr = __shfl_down(v.x, 1);
    if (q == 0) l = 0.f;
    if (q == 31) rr = 0.f;
    d[r][0] = (double)l;
    d[r][1] = (double)v.x;
    d[r][2] = (double)v.y;
    d[r][3] = (double)v.z;
    d[r][4] = (double)v.w;
    d[r][5] = (double)rr;
  }
  double tb[6];
  #pragma unroll
  for (int j = 0; j < 6; ++j) tb[j] = d[0][j] + d[2][j];
  #pragma unroll
  for (int i = 0; i < 4; ++i) {
    double c2 = d[1][i + 1];
    double f2 = (d[1][i] + d[1][i + 2]) + tb[i + 1];
    double e2 = tb[i] + tb[i + 2];
    P[i] = fma(w.w0, c2, fma(w.w1, f2, w.w2 * e2));
    Q[i] = fma(w.w1, c2, fma(w.w2, f2, w.w3 * e2));
  }
}

// cost-volume transform of 3 raw rows: cv = -|src(shift ox via shfl) - tgt|
__device__ __forceinline__ void cv_rows(const Raw& r, int q, int ox, float4 rows[3]) {
  #pragma unroll
  for (int dy = 0; dy < 3; ++dy) {
    float4 s4 = r.s[dy];
    float sl = __shfl_up(s4.w, 1);
    float sr = __shfl_down(s4.x, 1);
    if (q == 0) sl = 0.f;
    if (q == 31) sr = 0.f;
    float4 sh;
    if (ox < 0)      sh = make_float4(sl, s4.x, s4.y, s4.z);
    else if (ox > 0) sh = make_float4(s4.y, s4.z, s4.w, sr);
    else             sh = s4;
    float4 t4 = r.t[dy];
    rows[dy] = make_float4(-fabsf(__fsub_rn(sh.x, t4.x)), -fabsf(__fsub_rn(sh.y, t4.y)),
                           -fabsf(__fsub_rn(sh.z, t4.z)), -fabsf(__fsub_rn(sh.w, t4.w)));
  }
}

// Blur body. YSAFE=true keeps the per-row y-masks (edge y-tiles); YSAFE=false
// is the mask-free fast path for interior y-tiles. z-bounds are wave-uniform
// -> scalar branches. Values and f64 order identical in both paths.
template <bool FUSED, bool YSAFE>
__device__ __forceinline__ void blur_body(
    const float* __restrict__ inc, const float* __restrict__ src,
    const float* __restrict__ tgt, float* __restrict__ outc,
    const W4d& w, int q, int x0, int y, int z0, int z1,
    int oz, int oy, int ox) {
  bool mT0 = true, mT2 = true, mS0 = true, mS1 = true, mS2 = true;
  if (YSAFE) {
    mT0 = ((unsigned)(y - 1) < (unsigned)WW);
    mT2 = ((unsigned)(y + 1) < (unsigned)WW);
    if (FUSED) {
      mS0 = mT0 && ((unsigned)(y - 1 + oy) < (unsigned)WW);
      mS1 = ((unsigned)(y + oy) < (unsigned)WW);
      mS2 = mT2 && ((unsigned)(y + 1 + oy) < (unsigned)WW);
    }
  }
  const float* __restrict__ tb_ = (FUSED ? tgt : inc) + y * DD + x0;
  const float* __restrict__ sb_ = FUSED ? (src + (y + oy) * DD + x0) : nullptr;

  auto load_raw = [&](int zz, Raw& r) {
    if ((unsigned)zz < (unsigned)HH) {          // uniform (scalar) branch
      const float* bp = tb_ + (size_t)zz * SLICE;
      r.t[0] = (!YSAFE || mT0) ? *(const float4*)(bp - DD) : zf4();
      r.t[1] = *(const float4*)bp;
      r.t[2] = (!YSAFE || mT2) ? *(const float4*)(bp + DD) : zf4();
      if (FUSED) {
        int sz = zz + oz;
        if ((unsigned)sz < (unsigned)HH) {      // uniform branch
          const float* sp = sb_ + (size_t)sz * SLICE;
          r.s[0] = (!YSAFE || mS0) ? *(const float4*)(sp - DD) : zf4();
          r.s[1] = (!YSAFE || mS1) ? *(const float4*)(sp) : zf4();
          r.s[2] = (!YSAFE || mS2) ? *(const float4*)(sp + DD) : zf4();
        } else {
          r.s[0] = zf4(); r.s[1] = zf4(); r.s[2] = zf4();
        }
      }
    } else {
      r.t[0] = zf4(); r.t[1] = zf4(); r.t[2] = zf4();
      if (FUSED) { r.s[0] = zf4(); r.s[1] = zf4(); r.s[2] = zf4(); }
    }
  };

  auto finishF = [&](const Raw& r, double P[4], double Q[4]) {
    float4 rows[3];
    if (FUSED) cv_rows(r, q, ox, rows);
    else { rows[0] = r.t[0]; rows[1] = r.t[1]; rows[2] = r.t[2]; }
    pq_rows(rows, q, w, P, Q);
  };

  Raw rA, rB, rC, rD;
  load_raw(z0 - 1, rA);
  load_raw(z0, rB);
  load_raw(z0 + 1, rC);
  double Pd[4], Qm[4], Pc[4], Qc[4];
  finishF(rA, Pd, Qm);   // Pd dead -> DCE'd
  finishF(rB, Pc, Qc);
  float* ob = outc + y * DD + x0;
  for (int z = z0; z < z1; ++z) {
    load_raw(z + 2, rD);          // prefetch 2 ahead
    double Pn[4], Qn[4];
    finishF(rC, Pn, Qn);
    float4 o4;
    o4.x = (float)(Pc[0] + (Qm[0] + Qn[0]));
    o4.y = (float)(Pc[1] + (Qm[1] + Qn[1]));
    o4.z = (float)(Pc[2] + (Qm[2] + Qn[2]));
    o4.w = (float)(Pc[3] + (Qm[3] + Qn[3]));
    *(float4*)(ob + (size_t)z * SLICE) = o4;
    #pragma unroll
    for (int i = 0; i < 4; ++i) { Qm[i] = Qc[i]; Qc[i] = Qn[i]; Pc[i] = Pn[i]; }
    rC = rD;
  }
}

// Depthwise 3x3x3 Gaussian blur wrapper. Interior y-tiles -> mask-free body.
template <bool FUSED>
__global__ __launch_bounds__(256) void blur4_kernel(
    const float* __restrict__ in, const float* __restrict__ src,
    const float* __restrict__ tgt, float* __restrict__ out, int zslab, W4d w) {
  const int tid = threadIdx.x;
  const int lane = tid & 63;
  const int q = lane & 31;
  const int x0 = q << 2;
  const int y = blockIdx.x * 8 + ((tid >> 6) << 1) + (lane >> 5);
  const int c = blockIdx.z;
  const int z0 = blockIdx.y * zslab;
  const int z1 = min(z0 + zslab, HH);

  int oz = 0, oy = 0, ox = 0;
  if (FUSED) { oz = c / 9 - 1; oy = (c / 3) % 3 - 1; ox = c % 3 - 1; }
  const float* __restrict__ inc = FUSED ? (const float*)nullptr : (in + (size_t)c * NVOX);
  float* __restrict__ outc = out + (size_t)c * NVOX;

  const bool interior = (blockIdx.x > 0) && (blockIdx.x + 1 < gridDim.x);
  if (interior)
    blur_body<FUSED, false>(inc, src, tgt, outc, w, q, x0, y, z0, z1, oz, oy, ox);
  else
    blur_body<FUSED, true>(inc, src, tgt, outc, w, q, x0, y, z0, z1, oz, oy, ox);
}

// coupled[o] = cv[o] - coeff * ||flow - offset_o||^2 (un-fused rounds, matching
// numpy). Reference argmax = exact-equality ties on y_o = f32(coupled_o/temp);
// the division's coarse grid merges 1-ulp near-ties, which then SUM offsets.
// Tie sums in ONE packed u32 (6-bit fields; exact). 4 voxels/thread; channel
// loads in chunks of 9, DOUBLE-BUFFERED: chunk k+1's 9 loads issue before
// chunk k's compare chain, hiding L3 latency under ~200 VALU ops. Grid caps
// occupancy at ~15 waves/CU regardless, so the extra 36 VGPR are free
// (r9 lesson: 27-wide hoist spilled; 2x9 = 72 VGPR buffer does not).
template <int COUPLE>
__global__ __launch_bounds__(256) void flow4_kernel(
    const float* __restrict__ cv, const float* __restrict__ fin,
    float coeff, float* __restrict__ fout) {
  const int t = blockIdx.x * blockDim.x + threadIdx.x;
  const size_t v = (size_t)t * 4;
  if (v >= (size_t)NVOX) return;

  float fza[4] = {0, 0, 0, 0}, fya[4] = {0, 0, 0, 0}, fxa[4] = {0, 0, 0, 0};
  if (COUPLE) {
    float4 fz = *(const float4*)(fin + v);
    float4 fy = *(const float4*)(fin + (size_t)NVOX + v);
    float4 fx = *(const float4*)(fin + 2 * (size_t)NVOX + v);
    fza[0] = fz.x; fza[1] = fz.y; fza[2] = fz.z; fza[3] = fz.w;
    fya[0] = fy.x; fya[1] = fy.y; fya[2] = fy.z; fya[3] = fy.w;
    fxa[0] = fx.x; fxa[1] = fx.y; fxa[2] = fx.z; fxa[3] = fx.w;
  }
  float best[4] = {-INFINITY, -INFINITY, -INFINITY, -INFINITY};
  unsigned acc[4] = {0, 0, 0, 0};

  auto LOAD = [&](float4* buf, int ch) {
    #pragma unroll
    for (int j = 0; j < 9; ++j)
      buf[j] = *(const float4*)(cv + (size_t)(ch * 9 + j) * NVOX + v);
  };
  auto PROC = [&](const float4* buf, int ch) {
    #pragma unroll
    for (int j = 0; j < 9; ++j) {
      const int o = ch * 9 + j;
      const float ozf = (float)(o / 9 - 1);
      const float oyf = (float)((o / 3) % 3 - 1);
      const float oxf = (float)(o % 3 - 1);
      const unsigned packed = (1u << 18) | ((unsigned)(o / 9) << 12) |
                              ((unsigned)((o / 3) % 3) << 6) | (unsigned)(o % 3);
      float ca[4] = {buf[j].x, buf[j].y, buf[j].z, buf[j].w};
      #pragma unroll
      for (int i = 0; i < 4; ++i) {
        float cvv = ca[i];
        if (COUPLE) {
          float dz = __fsub_rn(fza[i], ozf);
          float dy = __fsub_rn(fya[i], oyf);
          float dx = __fsub_rn(fxa[i], oxf);
          float d2 = __fadd_rn(__fadd_rn(__fmul_rn(dz, dz), __fmul_rn(dy, dy)),
                               __fmul_rn(dx, dx));
          cvv = __fsub_rn(cvv, __fmul_rn(coeff, d2));
        }
        float yv = __fdiv_rn(cvv, 5e-5f);   // tie-merging quantization step
        bool gt = yv > best[i];
        bool eq = yv == best[i];
        best[i] = fmaxf(best[i], yv);
        unsigned upd = eq ? acc[i] + packed : acc[i];
        acc[i] = gt ? packed : upd;
      }
    }
  };

  float4 bufA[9], bufB[9];
  LOAD(bufA, 0);     // chunk 0 in flight
  LOAD(bufB, 1);     // chunk 1 in flight
  PROC(bufA, 0);     // consume 0 while 1 is landing
  LOAD(bufA, 2);     // chunk 2 in flight
  PROC(bufB, 1);     // consume 1 while 2 is landing
  PROC(bufA, 2);

  float s0[4], s1[4], s2[4];
  #pragma unroll
  for (int i = 0; i < 4; ++i) {
    int cnt = (int)((acc[i] >> 18) & 63u);
    s0[i] = (float)((int)((acc[i] >> 12) & 63u) - cnt);
    s1[i] = (float)((int)((acc[i] >> 6) & 63u) - cnt);
    s2[i] = (float)((int)(acc[i] & 63u) - cnt);
  }
  *(float4*)(fout + v) = make_float4(s0[0], s0[1], s0[2], s0[3]);
  *(float4*)(fout + (size_t)NVOX + v) = make_float4(s1[0], s1[1], s1[2], s1[3]);
  *(float4*)(fout + 2 * (size_t)NVOX + v) = make_float4(s2[0], s2[1], s2[2], s2[3]);
}

extern "C" void kernel_launch(void* const* d_in, const int* in_sizes, int n_in,
                              void* d_out, int out_size, void* d_ws, size_t ws_size,
                              hipStream_t stream) {
  const float* src = (const float*)d_in[0];
  const float* tgt = (const float*)d_in[1];
  float* out = (float*)d_out;

  // Workspace: cv1 27N (blurred cv, read-only after pass 3), cv2 27N (ping,
  // dead after pass 3 -> flow buffers alias there).
  float* cv1 = (float*)d_ws;
  float* cv2 = cv1 + (size_t)27 * NVOX;
  float* fa = cv2;
  float* fb = cv2 + (size_t)3 * NVOX;

  // 3^3 Gaussian (sigma=0.5) weights, replicating the reference's f32 path
  // (factor*exp in f32, numpy pairwise f32 sum, f32 divide).
  float wt[27];
  {
    volatile float factor = (float)(1.0 / pow(2.0 * M_PI * 0.25, 1.5));
    float g[27];
    int o = 0;
    for (int i = 0; i < 3; ++i)
      for (int j = 0; j < 3; ++j)
        for (int k = 0; k < 3; ++k) {
          int d2 = (i - 1) * (i - 1) + (j - 1) * (j - 1) + (k - 1) * (k - 1);
          volatile float e = (float)exp(-2.0 * (double)d2);
          volatile float gg = factor * e;
          g[o++] = gg;
        }
    volatile float r[8];
    for (int j = 0; j < 8; ++j) r[j] = g[j];
    for (int j = 0; j < 8; ++j) r[j] = r[j] + g[8 + j];
    for (int j = 0; j < 8; ++j) r[j] = r[j] + g[16 + j];
    volatile float t01 = r[0] + r[1];
    volatile float t23 = r[2] + r[3];
    volatile float t45 = r[4] + r[5];
    volatile float t67 = r[6] + r[7];
    volatile float h0 = t01 + t23;
    volatile float h1 = t45 + t67;
    volatile float s = h0 + h1;
    s = s + g[24];
    s = s + g[25];
    s = s + g[26];
    for (int t = 0; t < 27; ++t) {
      volatile float w = g[t] / s;
      wt[t] = w;
    }
  }
  // 4 distinct weight values by d^2 symmetry: center/face/edge/corner.
  W4d wd = {(double)wt[13], (double)wt[12], (double)wt[9], (double)wt[0]};

  dim3 blk(256);
  // r10 knee: big zslab=6 -> 4320 blocks; small zslab=2 -> 1440; flow 960.
  dim3 gBig(WW / 8, HH / 6, 27);
  dim3 gSm(WW / 8, HH / 2, 3);
  int fblocks = NVOX / 4 / 256;    // 960

  // cv blur passes (pass 1 computes cv on the fly from src/tgt)
  blur4_kernel<true><<<gBig, blk, 0, stream>>>(nullptr, src, tgt, cv1, 6, wd);
  blur4_kernel<false><<<gBig, blk, 0, stream>>>(cv1, nullptr, nullptr, cv2, 6, wd);
  blur4_kernel<false><<<gBig, blk, 0, stream>>>(cv2, nullptr, nullptr, cv1, 6, wd);
  // initial argmax flow (cv2 now dead -> fa/fb live there)
  flow4_kernel<0><<<fblocks, blk, 0, stream>>>(cv1, nullptr, 0.f, fa);
  blur4_kernel<false><<<gSm, blk, 0, stream>>>(fa, nullptr, nullptr, fb, 2, wd);
  blur4_kernel<false><<<gSm, blk, 0, stream>>>(fb, nullptr, nullptr, fa, 2, wd);
  blur4_kernel<false><<<gSm, blk, 0, stream>>>(fa, nullptr, nullptr, fb, 2, wd);
  // six coupling iterations
  const float coefs[6] = {0.003f, 0.01f, 0.03f, 0.1f, 0.3f, 1.0f};
  for (int it = 0; it < 6; ++it) {
    flow4_kernel<1><<<fblocks, blk, 0, stream>>>(cv1, fb, coefs[it], fa);
    blur4_kernel<false><<<gSm, blk, 0, stream>>>(fa, nullptr, nullptr, fb, 2, wd);
    blur4_kernel<false><<<gSm, blk, 0, stream>>>(fb, nullptr, nullptr, fa, 2, wd);
    float* dst = (it == 5) ? out : fb;
    blur4_kernel<false><<<gSm, blk, 0, stream>>>(fa, nullptr, nullptr, dst, 2, wd);
  }
}

// Round 15
// 528.518 us; speedup vs baseline: 1.0081x; 1.0081x over previous
//
#include <hip/hip_runtime.h>
#include <math.h>

// Problem constants (reference: H, W, D = 96, 80, 128; KS=1 -> 27 offsets)
#define HH 96
#define WW 80
#define DD 128
#define SLICE (WW * DD)       // 10240
#define NVOX (HH * WW * DD)   // 983040

struct W4d { double w0, w1, w2, w3; };
struct Raw { float4 t[3]; float4 s[3]; };

__device__ __forceinline__ float4 zf4() { return make_float4(0.f, 0.f, 0.f, 0.f); }

// f64 2D 9-tap combine of one slice (3 rows x 6 cols incl. shfl halo) into
// P = w0*c + w1*f + w2*e and Q = w1*c + w2*f + w3*e (d^2 weight classes).
// out3d(z) = P(z) + Q(z-1) + Q(z+1), rounded once to f32 => correctly-rounded
// conv up to ~1e-16 f64 reassociation.
__device__ __forceinline__ void pq_rows(const float4 rows[3], int q, const W4d& w,
                                        double P[4], double Q[4]) {
  double d[3][6];
  #pragma unroll
  for (int r = 0; r < 3; ++r) {
    float4 v = rows[r];
    float l = __shfl_up(v.w, 1);
    float rr = __shfl_down(v.x, 1);
    if (q == 0) l = 0.f;
    if (q == 31) rr = 0.f;
    d[r][0] = (double)l;
    d[r][1] = (double)v.x;
    d[r][2] = (double)v.y;
    d[r][3] = (double)v.z;
    d[r][4] = (double)v.w;
    d[r][5] = (double)rr;
  }
  double tb[6];
  #pragma unroll
  for (int j = 0; j < 6; ++j) tb[j] = d[0][j] + d[2][j];
  #pragma unroll
  for (int i = 0; i < 4; ++i) {
    double c2 = d[1][i + 1];
    double f2 = (d[1][i] + d[1][i + 2]) + tb[i + 1];
    double e2 = tb[i] + tb[i + 2];
    P[i] = fma(w.w0, c2, fma(w.w1, f2, w.w2 * e2));
    Q[i] = fma(w.w1, c2, fma(w.w2, f2, w.w3 * e2));
  }
}

// cost-volume transform of 3 raw rows: cv = -|src(shift ox via shfl) - tgt|
__device__ __forceinline__ void cv_rows(const Raw& r, int q, int ox, float4 rows[3]) {
  #pragma unroll
  for (int dy = 0; dy < 3; ++dy) {
    float4 s4 = r.s[dy];
    float sl = __shfl_up(s4.w, 1);
    float sr = __shfl_down(s4.x, 1);
    if (q == 0) sl = 0.f;
    if (q == 31) sr = 0.f;
    float4 sh;
    if (ox < 0)      sh = make_float4(sl, s4.x, s4.y, s4.z);
    else if (ox > 0) sh = make_float4(s4.y, s4.z, s4.w, sr);
    else             sh = s4;
    float4 t4 = r.t[dy];
    rows[dy] = make_float4(-fabsf(__fsub_rn(sh.x, t4.x)), -fabsf(__fsub_rn(sh.y, t4.y)),
                           -fabsf(__fsub_rn(sh.z, t4.z)), -fabsf(__fsub_rn(sh.w, t4.w)));
  }
}

// Blur body. YSAFE=true keeps per-row y-masks (edge y-tiles); YSAFE=false is
// the mask-free interior path. ZS is a COMPILE-TIME slab: the z-march fully
// unrolls, so the 3-slice software pipeline rotates by register renaming
// (no rC=rD / P,Q shift movs) and slice addressing folds into immediates.
// f64 ops and order identical to the runtime-loop version -> bit-identical.
template <bool FUSED, bool YSAFE, int ZS>
__device__ __forceinline__ void blur_body(
    const float* __restrict__ inc, const float* __restrict__ src,
    const float* __restrict__ tgt, float* __restrict__ outc,
    const W4d& w, int q, int x0, int y, int z0,
    int oz, int oy, int ox) {
  bool mT0 = true, mT2 = true, mS0 = true, mS1 = true, mS2 = true;
  if (YSAFE) {
    mT0 = ((unsigned)(y - 1) < (unsigned)WW);
    mT2 = ((unsigned)(y + 1) < (unsigned)WW);
    if (FUSED) {
      mS0 = mT0 && ((unsigned)(y - 1 + oy) < (unsigned)WW);
      mS1 = ((unsigned)(y + oy) < (unsigned)WW);
      mS2 = mT2 && ((unsigned)(y + 1 + oy) < (unsigned)WW);
    }
  }
  const float* __restrict__ tb_ = (FUSED ? tgt : inc) + y * DD + x0;
  const float* __restrict__ sb_ = FUSED ? (src + (y + oy) * DD + x0) : nullptr;

  auto load_raw = [&](int zz, Raw& r) {
    if ((unsigned)zz < (unsigned)HH) {          // uniform (scalar) branch
      const float* bp = tb_ + (size_t)zz * SLICE;
      r.t[0] = (!YSAFE || mT0) ? *(const float4*)(bp - DD) : zf4();
      r.t[1] = *(const float4*)bp;
      r.t[2] = (!YSAFE || mT2) ? *(const float4*)(bp + DD) : zf4();
      if (FUSED) {
        int sz = zz + oz;
        if ((unsigned)sz < (unsigned)HH) {      // uniform branch
          const float* sp = sb_ + (size_t)sz * SLICE;
          r.s[0] = (!YSAFE || mS0) ? *(const float4*)(sp - DD) : zf4();
          r.s[1] = (!YSAFE || mS1) ? *(const float4*)(sp) : zf4();
          r.s[2] = (!YSAFE || mS2) ? *(const float4*)(sp + DD) : zf4();
        } else {
          r.s[0] = zf4(); r.s[1] = zf4(); r.s[2] = zf4();
        }
      }
    } else {
      r.t[0] = zf4(); r.t[1] = zf4(); r.t[2] = zf4();
      if (FUSED) { r.s[0] = zf4(); r.s[1] = zf4(); r.s[2] = zf4(); }
    }
  };

  auto finishF = [&](const Raw& r, double P[4], double Q[4]) {
    float4 rows[3];
    if (FUSED) cv_rows(r, q, ox, rows);
    else { rows[0] = r.t[0]; rows[1] = r.t[1]; rows[2] = r.t[2]; }
    pq_rows(rows, q, w, P, Q);
  };

  Raw rA, rB, rC, rD;
  load_raw(z0 - 1, rA);
  load_raw(z0, rB);
  load_raw(z0 + 1, rC);
  double Pd[4], Qm[4], Pc[4], Qc[4];
  finishF(rA, Pd, Qm);   // Pd dead -> DCE'd
  finishF(rB, Pc, Qc);
  float* ob = outc + y * DD + x0;
  #pragma unroll
  for (int zi = 0; zi < ZS; ++zi) {
    const int z = z0 + zi;
    load_raw(z + 2, rD);          // prefetch 2 ahead
    double Pn[4], Qn[4];
    finishF(rC, Pn, Qn);
    float4 o4;
    o4.x = (float)(Pc[0] + (Qm[0] + Qn[0]));
    o4.y = (float)(Pc[1] + (Qm[1] + Qn[1]));
    o4.z = (float)(Pc[2] + (Qm[2] + Qn[2]));
    o4.w = (float)(Pc[3] + (Qm[3] + Qn[3]));
    *(float4*)(ob + (size_t)z * SLICE) = o4;
    #pragma unroll
    for (int i = 0; i < 4; ++i) { Qm[i] = Qc[i]; Qc[i] = Qn[i]; Pc[i] = Pn[i]; }
    rC = rD;                      // renamed away by full unroll
  }
}

// Depthwise 3x3x3 Gaussian blur wrapper. Interior y-tiles -> mask-free body.
template <bool FUSED, int ZS>
__global__ __launch_bounds__(256) void blur4_kernel(
    const float* __restrict__ in, const float* __restrict__ src,
    const float* __restrict__ tgt, float* __restrict__ out, W4d w) {
  const int tid = threadIdx.x;
  const int lane = tid & 63;
  const int q = lane & 31;
  const int x0 = q << 2;
  const int y = blockIdx.x * 8 + ((tid >> 6) << 1) + (lane >> 5);
  const int c = blockIdx.z;
  const int z0 = blockIdx.y * ZS;   // HH % ZS == 0

  int oz = 0, oy = 0, ox = 0;
  if (FUSED) { oz = c / 9 - 1; oy = (c / 3) % 3 - 1; ox = c % 3 - 1; }
  const float* __restrict__ inc = FUSED ? (const float*)nullptr : (in + (size_t)c * NVOX);
  float* __restrict__ outc = out + (size_t)c * NVOX;

  const bool interior = (blockIdx.x > 0) && (blockIdx.x + 1 < gridDim.x);
  if (interior)
    blur_body<FUSED, false, ZS>(inc, src, tgt, outc, w, q, x0, y, z0, oz, oy, ox);
  else
    blur_body<FUSED, true, ZS>(inc, src, tgt, outc, w, q, x0, y, z0, oz, oy, ox);
}

// coupled[o] = cv[o] - coeff * ||flow - offset_o||^2 (un-fused rounds, matching
// numpy). Reference argmax = exact-equality ties on y_o = f32(coupled_o/temp);
// the division's coarse grid merges 1-ulp near-ties, which then SUM offsets.
// Tie sums in ONE packed u32 (6-bit fields; exact). 4 voxels/thread; chunk-9
// double-buffered loads (r14; at the grid-capped occupancy the extra VGPRs
// are free). Flow measured at its ~4.3 TB/s L3-streaming floor.
template <int COUPLE>
__global__ __launch_bounds__(256) void flow4_kernel(
    const float* __restrict__ cv, const float* __restrict__ fin,
    float coeff, float* __restrict__ fout) {
  const int t = blockIdx.x * blockDim.x + threadIdx.x;
  const size_t v = (size_t)t * 4;
  if (v >= (size_t)NVOX) return;

  float fza[4] = {0, 0, 0, 0}, fya[4] = {0, 0, 0, 0}, fxa[4] = {0, 0, 0, 0};
  if (COUPLE) {
    float4 fz = *(const float4*)(fin + v);
    float4 fy = *(const float4*)(fin + (size_t)NVOX + v);
    float4 fx = *(const float4*)(fin + 2 * (size_t)NVOX + v);
    fza[0] = fz.x; fza[1] = fz.y; fza[2] = fz.z; fza[3] = fz.w;
    fya[0] = fy.x; fya[1] = fy.y; fya[2] = fy.z; fya[3] = fy.w;
    fxa[0] = fx.x; fxa[1] = fx.y; fxa[2] = fx.z; fxa[3] = fx.w;
  }
  float best[4] = {-INFINITY, -INFINITY, -INFINITY, -INFINITY};
  unsigned acc[4] = {0, 0, 0, 0};

  auto LOAD = [&](float4* buf, int ch) {
    #pragma unroll
    for (int j = 0; j < 9; ++j)
      buf[j] = *(const float4*)(cv + (size_t)(ch * 9 + j) * NVOX + v);
  };
  auto PROC = [&](const float4* buf, int ch) {
    #pragma unroll
    for (int j = 0; j < 9; ++j) {
      const int o = ch * 9 + j;
      const float ozf = (float)(o / 9 - 1);
      const float oyf = (float)((o / 3) % 3 - 1);
      const float oxf = (float)(o % 3 - 1);
      const unsigned packed = (1u << 18) | ((unsigned)(o / 9) << 12) |
                              ((unsigned)((o / 3) % 3) << 6) | (unsigned)(o % 3);
      float ca[4] = {buf[j].x, buf[j].y, buf[j].z, buf[j].w};
      #pragma unroll
      for (int i = 0; i < 4; ++i) {
        float cvv = ca[i];
        if (COUPLE) {
          float dz = __fsub_rn(fza[i], ozf);
          float dy = __fsub_rn(fya[i], oyf);
          float dx = __fsub_rn(fxa[i], oxf);
          float d2 = __fadd_rn(__fadd_rn(__fmul_rn(dz, dz), __fmul_rn(dy, dy)),
                               __fmul_rn(dx, dx));
          cvv = __fsub_rn(cvv, __fmul_rn(coeff, d2));
        }
        float yv = __fdiv_rn(cvv, 5e-5f);   // tie-merging quantization step
        bool gt = yv > best[i];
        bool eq = yv == best[i];
        best[i] = fmaxf(best[i], yv);
        unsigned upd = eq ? acc[i] + packed : acc[i];
        acc[i] = gt ? packed : upd;
      }
    }
  };

  float4 bufA[9], bufB[9];
  LOAD(bufA, 0);
  LOAD(bufB, 1);
  PROC(bufA, 0);
  LOAD(bufA, 2);
  PROC(bufB, 1);
  PROC(bufA, 2);

  float s0[4], s1[4], s2[4];
  #pragma unroll
  for (int i = 0; i < 4; ++i) {
    int cnt = (int)((acc[i] >> 18) & 63u);
    s0[i] = (float)((int)((acc[i] >> 12) & 63u) - cnt);
    s1[i] = (float)((int)((acc[i] >> 6) & 63u) - cnt);
    s2[i] = (float)((int)(acc[i] & 63u) - cnt);
  }
  *(float4*)(fout + v) = make_float4(s0[0], s0[1], s0[2], s0[3]);
  *(float4*)(fout + (size_t)NVOX + v) = make_float4(s1[0], s1[1], s1[2], s1[3]);
  *(float4*)(fout + 2 * (size_t)NVOX + v) = make_float4(s2[0], s2[1], s2[2], s2[3]);
}

extern "C" void kernel_launch(void* const* d_in, const int* in_sizes, int n_in,
                              void* d_out, int out_size, void* d_ws, size_t ws_size,
                              hipStream_t stream) {
  const float* src = (const float*)d_in[0];
  const float* tgt = (const float*)d_in[1];
  float* out = (float*)d_out;

  // Workspace: cv1 27N (blurred cv, read-only after pass 3), cv2 27N (ping,
  // dead after pass 3 -> flow buffers alias there).
  float* cv1 = (float*)d_ws;
  float* cv2 = cv1 + (size_t)27 * NVOX;
  float* fa = cv2;
  float* fb = cv2 + (size_t)3 * NVOX;

  // 3^3 Gaussian (sigma=0.5) weights, replicating the reference's f32 path
  // (factor*exp in f32, numpy pairwise f32 sum, f32 divide).
  float wt[27];
  {
    volatile float factor = (float)(1.0 / pow(2.0 * M_PI * 0.25, 1.5));
    float g[27];
    int o = 0;
    for (int i = 0; i < 3; ++i)
      for (int j = 0; j < 3; ++j)
        for (int k = 0; k < 3; ++k) {
          int d2 = (i - 1) * (i - 1) + (j - 1) * (j - 1) + (k - 1) * (k - 1);
          volatile float e = (float)exp(-2.0 * (double)d2);
          volatile float gg = factor * e;
          g[o++] = gg;
        }
    volatile float r[8];
    for (int j = 0; j < 8; ++j) r[j] = g[j];
    for (int j = 0; j < 8; ++j) r[j] = r[j] + g[8 + j];
    for (int j = 0; j < 8; ++j) r[j] = r[j] + g[16 + j];
    volatile float t01 = r[0] + r[1];
    volatile float t23 = r[2] + r[3];
    volatile float t45 = r[4] + r[5];
    volatile float t67 = r[6] + r[7];
    volatile float h0 = t01 + t23;
    volatile float h1 = t45 + t67;
    volatile float s = h0 + h1;
    s = s + g[24];
    s = s + g[25];
    s = s + g[26];
    for (int t = 0; t < 27; ++t) {
      volatile float w = g[t] / s;
      wt[t] = w;
    }
  }
  // 4 distinct weight values by d^2 symmetry: center/face/edge/corner.
  W4d wd = {(double)wt[13], (double)wt[12], (double)wt[9], (double)wt[0]};

  dim3 blk(256);
  // Big: ZS=6 -> 4320 blocks; small: ZS=2 -> 1440; flow: 960 (r10 knee).
  dim3 gBig(WW / 8, HH / 6, 27);
  dim3 gSm(WW / 8, HH / 2, 3);
  int fblocks = NVOX / 4 / 256;    // 960

  // cv blur passes (pass 1 computes cv on the fly from src/tgt)
  blur4_kernel<true, 6><<<gBig, blk, 0, stream>>>(nullptr, src, tgt, cv1, wd);
  blur4_kernel<false, 6><<<gBig, blk, 0, stream>>>(cv1, nullptr, nullptr, cv2, wd);
  blur4_kernel<false, 6><<<gBig, blk, 0, stream>>>(cv2, nullptr, nullptr, cv1, wd);
  // initial argmax flow (cv2 now dead -> fa/fb live there)
  flow4_kernel<0><<<fblocks, blk, 0, stream>>>(cv1, nullptr, 0.f, fa);
  blur4_kernel<false, 2><<<gSm, blk, 0, stream>>>(fa, nullptr, nullptr, fb, wd);
  blur4_kernel<false, 2><<<gSm, blk, 0, stream>>>(fb, nullptr, nullptr, fa, wd);
  blur4_kernel<false, 2><<<gSm, blk, 0, stream>>>(fa, nullptr, nullptr, fb, wd);
  // six coupling iterations
  const float coefs[6] = {0.003f, 0.01f, 0.03f, 0.1f, 0.3f, 1.0f};
  for (int it = 0; it < 6; ++it) {
    flow4_kernel<1><<<fblocks, blk, 0, stream>>>(cv1, fb, coefs[it], fa);
    blur4_kernel<false, 2><<<gSm, blk, 0, stream>>>(fa, nullptr, nullptr, fb, wd);
    blur4_kernel<false, 2><<<gSm, blk, 0, stream>>>(fb, nullptr, nullptr, fa, wd);
    float* dst = (it == 5) ? out : fb;
    blur4_kernel<false, 2><<<gSm, blk, 0, stream>>>(fa, nullptr, nullptr, dst, wd);
  }
}

// Round 16
// 528.358 us; speedup vs baseline: 1.0084x; 1.0003x over previous
//
#include <hip/hip_runtime.h>
#include <math.h>

// Problem constants (reference: H, W, D = 96, 80, 128; KS=1 -> 27 offsets)
#define HH 96
#define WW 80
#define DD 128
#define SLICE (WW * DD)       // 10240
#define NVOX (HH * WW * DD)   // 983040

struct W4d { double w0, w1, w2, w3; };
struct Raw { float4 t[3]; float4 s[3]; };

__device__ __forceinline__ float4 zf4() { return make_float4(0.f, 0.f, 0.f, 0.f); }

// f64 2D 9-tap combine of one slice (3 rows x 6 cols incl. shfl halo) into
// P = w0*c + w1*f + w2*e and Q = w1*c + w2*f + w3*e (d^2 weight classes).
// out3d(z) = P(z) + Q(z-1) + Q(z+1), rounded once to f32 => correctly-rounded
// conv up to ~1e-16 f64 reassociation.
__device__ __forceinline__ void pq_rows(const float4 rows[3], int q, const W4d& w,
                                        double P[4], double Q[4]) {
  double d[3][6];
  #pragma unroll
  for (int r = 0; r < 3; ++r) {
    float4 v = rows[r];
    float l = __shfl_up(v.w, 1);
    float rr = __shfl_down(v.x, 1);
    if (q == 0) l = 0.f;
    if (q == 31) rr = 0.f;
    d[r][0] = (double)l;
    d[r][1] = (double)v.x;
    d[r][2] = (double)v.y;
    d[r][3] = (double)v.z;
    d[r][4] = (double)v.w;
    d[r][5] = (double)rr;
  }
  double tb[6];
  #pragma unroll
  for (int j = 0; j < 6; ++j) tb[j] = d[0][j] + d[2][j];
  #pragma unroll
  for (int i = 0; i < 4; ++i) {
    double c2 = d[1][i + 1];
    double f2 = (d[1][i] + d[1][i + 2]) + tb[i + 1];
    double e2 = tb[i] + tb[i + 2];
    P[i] = fma(w.w0, c2, fma(w.w1, f2, w.w2 * e2));
    Q[i] = fma(w.w1, c2, fma(w.w2, f2, w.w3 * e2));
  }
}

// cost-volume transform of 3 raw rows: cv = -|src(shift ox via shfl) - tgt|
__device__ __forceinline__ void cv_rows(const Raw& r, int q, int ox, float4 rows[3]) {
  #pragma unroll
  for (int dy = 0; dy < 3; ++dy) {
    float4 s4 = r.s[dy];
    float sl = __shfl_up(s4.w, 1);
    float sr = __shfl_down(s4.x, 1);
    if (q == 0) sl = 0.f;
    if (q == 31) sr = 0.f;
    float4 sh;
    if (ox < 0)      sh = make_float4(sl, s4.x, s4.y, s4.z);
    else if (ox > 0) sh = make_float4(s4.y, s4.z, s4.w, sr);
    else             sh = s4;
    float4 t4 = r.t[dy];
    rows[dy] = make_float4(-fabsf(__fsub_rn(sh.x, t4.x)), -fabsf(__fsub_rn(sh.y, t4.y)),
                           -fabsf(__fsub_rn(sh.z, t4.z)), -fabsf(__fsub_rn(sh.w, t4.w)));
  }
}

// Blur body. YSAFE=true keeps per-row y-masks (edge y-tiles); YSAFE=false is
// the mask-free interior path. ZS=0: runtime z-loop (big blur — keeps VGPR at
// 52 for occupancy, r13's measured best). ZS>0: compile-time unrolled z-march
// (small blurs — removes pipeline-shift movs; VGPR stays low at ZS=2).
// f64 ops and order identical in all paths -> bit-identical output.
template <bool FUSED, bool YSAFE, int ZS>
__device__ __forceinline__ void blur_body(
    const float* __restrict__ inc, const float* __restrict__ src,
    const float* __restrict__ tgt, float* __restrict__ outc,
    const W4d& w, int q, int x0, int y, int z0, int zslab_rt,
    int oz, int oy, int ox) {
  bool mT0 = true, mT2 = true, mS0 = true, mS1 = true, mS2 = true;
  if (YSAFE) {
    mT0 = ((unsigned)(y - 1) < (unsigned)WW);
    mT2 = ((unsigned)(y + 1) < (unsigned)WW);
    if (FUSED) {
      mS0 = mT0 && ((unsigned)(y - 1 + oy) < (unsigned)WW);
      mS1 = ((unsigned)(y + oy) < (unsigned)WW);
      mS2 = mT2 && ((unsigned)(y + 1 + oy) < (unsigned)WW);
    }
  }
  const float* __restrict__ tb_ = (FUSED ? tgt : inc) + y * DD + x0;
  const float* __restrict__ sb_ = FUSED ? (src + (y + oy) * DD + x0) : nullptr;

  auto load_raw = [&](int zz, Raw& r) {
    if ((unsigned)zz < (unsigned)HH) {          // uniform (scalar) branch
      const float* bp = tb_ + (size_t)zz * SLICE;
      r.t[0] = (!YSAFE || mT0) ? *(const float4*)(bp - DD) : zf4();
      r.t[1] = *(const float4*)bp;
      r.t[2] = (!YSAFE || mT2) ? *(const float4*)(bp + DD) : zf4();
      if (FUSED) {
        int sz = zz + oz;
        if ((unsigned)sz < (unsigned)HH) {      // uniform branch
          const float* sp = sb_ + (size_t)sz * SLICE;
          r.s[0] = (!YSAFE || mS0) ? *(const float4*)(sp - DD) : zf4();
          r.s[1] = (!YSAFE || mS1) ? *(const float4*)(sp) : zf4();
          r.s[2] = (!YSAFE || mS2) ? *(const float4*)(sp + DD) : zf4();
        } else {
          r.s[0] = zf4(); r.s[1] = zf4(); r.s[2] = zf4();
        }
      }
    } else {
      r.t[0] = zf4(); r.t[1] = zf4(); r.t[2] = zf4();
      if (FUSED) { r.s[0] = zf4(); r.s[1] = zf4(); r.s[2] = zf4(); }
    }
  };

  auto finishF = [&](const Raw& r, double P[4], double Q[4]) {
    float4 rows[3];
    if (FUSED) cv_rows(r, q, ox, rows);
    else { rows[0] = r.t[0]; rows[1] = r.t[1]; rows[2] = r.t[2]; }
    pq_rows(rows, q, w, P, Q);
  };

  Raw rA, rB, rC, rD;
  load_raw(z0 - 1, rA);
  load_raw(z0, rB);
  load_raw(z0 + 1, rC);
  double Pd[4], Qm[4], Pc[4], Qc[4];
  finishF(rA, Pd, Qm);   // Pd dead -> DCE'd
  finishF(rB, Pc, Qc);
  float* ob = outc + y * DD + x0;

  auto step = [&](int z) {
    load_raw(z + 2, rD);          // prefetch 2 ahead
    double Pn[4], Qn[4];
    finishF(rC, Pn, Qn);
    float4 o4;
    o4.x = (float)(Pc[0] + (Qm[0] + Qn[0]));
    o4.y = (float)(Pc[1] + (Qm[1] + Qn[1]));
    o4.z = (float)(Pc[2] + (Qm[2] + Qn[2]));
    o4.w = (float)(Pc[3] + (Qm[3] + Qn[3]));
    *(float4*)(ob + (size_t)z * SLICE) = o4;
    #pragma unroll
    for (int i = 0; i < 4; ++i) { Qm[i] = Qc[i]; Qc[i] = Qn[i]; Pc[i] = Pn[i]; }
    rC = rD;
  };

  if constexpr (ZS > 0) {
    #pragma unroll
    for (int zi = 0; zi < ZS; ++zi) step(z0 + zi);
  } else {
    const int z1 = min(z0 + zslab_rt, HH);
    for (int z = z0; z < z1; ++z) step(z);
  }
}

// Depthwise 3x3x3 Gaussian blur wrapper. Interior y-tiles -> mask-free body.
template <bool FUSED, int ZS>
__global__ __launch_bounds__(256) void blur4_kernel(
    const float* __restrict__ in, const float* __restrict__ src,
    const float* __restrict__ tgt, float* __restrict__ out, int zslab_rt, W4d w) {
  const int tid = threadIdx.x;
  const int lane = tid & 63;
  const int q = lane & 31;
  const int x0 = q << 2;
  const int y = blockIdx.x * 8 + ((tid >> 6) << 1) + (lane >> 5);
  const int c = blockIdx.z;
  const int zstep = (ZS > 0) ? ZS : zslab_rt;
  const int z0 = blockIdx.y * zstep;

  int oz = 0, oy = 0, ox = 0;
  if (FUSED) { oz = c / 9 - 1; oy = (c / 3) % 3 - 1; ox = c % 3 - 1; }
  const float* __restrict__ inc = FUSED ? (const float*)nullptr : (in + (size_t)c * NVOX);
  float* __restrict__ outc = out + (size_t)c * NVOX;

  const bool interior = (blockIdx.x > 0) && (blockIdx.x + 1 < gridDim.x);
  if (interior)
    blur_body<FUSED, false, ZS>(inc, src, tgt, outc, w, q, x0, y, z0, zslab_rt, oz, oy, ox);
  else
    blur_body<FUSED, true, ZS>(inc, src, tgt, outc, w, q, x0, y, z0, zslab_rt, oz, oy, ox);
}

// coupled[o] = cv[o] - coeff * ||flow - offset_o||^2 (un-fused rounds, matching
// numpy). Reference argmax = exact-equality ties on y_o = f32(coupled_o/temp);
// the division's coarse grid merges 1-ulp near-ties, which then SUM offsets.
// Tie sums in ONE packed u32 (6-bit fields; exact). 4 voxels/thread; chunk-9
// double-buffered loads. Measured at its ~3.5-4 TB/s L3-streaming floor.
template <int COUPLE>
__global__ __launch_bounds__(256) void flow4_kernel(
    const float* __restrict__ cv, const float* __restrict__ fin,
    float coeff, float* __restrict__ fout) {
  const int t = blockIdx.x * blockDim.x + threadIdx.x;
  const size_t v = (size_t)t * 4;
  if (v >= (size_t)NVOX) return;

  float fza[4] = {0, 0, 0, 0}, fya[4] = {0, 0, 0, 0}, fxa[4] = {0, 0, 0, 0};
  if (COUPLE) {
    float4 fz = *(const float4*)(fin + v);
    float4 fy = *(const float4*)(fin + (size_t)NVOX + v);
    float4 fx = *(const float4*)(fin + 2 * (size_t)NVOX + v);
    fza[0] = fz.x; fza[1] = fz.y; fza[2] = fz.z; fza[3] = fz.w;
    fya[0] = fy.x; fya[1] = fy.y; fya[2] = fy.z; fya[3] = fy.w;
    fxa[0] = fx.x; fxa[1] = fx.y; fxa[2] = fx.z; fxa[3] = fx.w;
  }
  float best[4] = {-INFINITY, -INFINITY, -INFINITY, -INFINITY};
  unsigned acc[4] = {0, 0, 0, 0};

  auto LOAD = [&](float4* buf, int ch) {
    #pragma unroll
    for (int j = 0; j < 9; ++j)
      buf[j] = *(const float4*)(cv + (size_t)(ch * 9 + j) * NVOX + v);
  };
  auto PROC = [&](const float4* buf, int ch) {
    #pragma unroll
    for (int j = 0; j < 9; ++j) {
      const int o = ch * 9 + j;
      const float ozf = (float)(o / 9 - 1);
      const float oyf = (float)((o / 3) % 3 - 1);
      const float oxf = (float)(o % 3 - 1);
      const unsigned packed = (1u << 18) | ((unsigned)(o / 9) << 12) |
                              ((unsigned)((o / 3) % 3) << 6) | (unsigned)(o % 3);
      float ca[4] = {buf[j].x, buf[j].y, buf[j].z, buf[j].w};
      #pragma unroll
      for (int i = 0; i < 4; ++i) {
        float cvv = ca[i];
        if (COUPLE) {
          float dz = __fsub_rn(fza[i], ozf);
          float dy = __fsub_rn(fya[i], oyf);
          float dx = __fsub_rn(fxa[i], oxf);
          float d2 = __fadd_rn(__fadd_rn(__fmul_rn(dz, dz), __fmul_rn(dy, dy)),
                               __fmul_rn(dx, dx));
          cvv = __fsub_rn(cvv, __fmul_rn(coeff, d2));
        }
        float yv = __fdiv_rn(cvv, 5e-5f);   // tie-merging quantization step
        bool gt = yv > best[i];
        bool eq = yv == best[i];
        best[i] = fmaxf(best[i], yv);
        unsigned upd = eq ? acc[i] + packed : acc[i];
        acc[i] = gt ? packed : upd;
      }
    }
  };

  float4 bufA[9], bufB[9];
  LOAD(bufA, 0);
  LOAD(bufB, 1);
  PROC(bufA, 0);
  LOAD(bufA, 2);
  PROC(bufB, 1);
  PROC(bufA, 2);

  float s0[4], s1[4], s2[4];
  #pragma unroll
  for (int i = 0; i < 4; ++i) {
    int cnt = (int)((acc[i] >> 18) & 63u);
    s0[i] = (float)((int)((acc[i] >> 12) & 63u) - cnt);
    s1[i] = (float)((int)((acc[i] >> 6) & 63u) - cnt);
    s2[i] = (float)((int)(acc[i] & 63u) - cnt);
  }
  *(float4*)(fout + v) = make_float4(s0[0], s0[1], s0[2], s0[3]);
  *(float4*)(fout + (size_t)NVOX + v) = make_float4(s1[0], s1[1], s1[2], s1[3]);
  *(float4*)(fout + 2 * (size_t)NVOX + v) = make_float4(s2[0], s2[1], s2[2], s2[3]);
}

extern "C" void kernel_launch(void* const* d_in, const int* in_sizes, int n_in,
                              void* d_out, int out_size, void* d_ws, size_t ws_size,
                              hipStream_t stream) {
  const float* src = (const float*)d_in[0];
  const float* tgt = (const float*)d_in[1];
  float* out = (float*)d_out;

  // Workspace: cv1 27N (blurred cv, read-only after pass 3), cv2 27N (ping,
  // dead after pass 3 -> flow buffers alias there).
  float* cv1 = (float*)d_ws;
  float* cv2 = cv1 + (size_t)27 * NVOX;
  float* fa = cv2;
  float* fb = cv2 + (size_t)3 * NVOX;

  // 3^3 Gaussian (sigma=0.5) weights, replicating the reference's f32 path
  // (factor*exp in f32, numpy pairwise f32 sum, f32 divide).
  float wt[27];
  {
    volatile float factor = (float)(1.0 / pow(2.0 * M_PI * 0.25, 1.5));
    float g[27];
    int o = 0;
    for (int i = 0; i < 3; ++i)
      for (int j = 0; j < 3; ++j)
        for (int k = 0; k < 3; ++k) {
          int d2 = (i - 1) * (i - 1) + (j - 1) * (j - 1) + (k - 1) * (k - 1);
          volatile float e = (float)exp(-2.0 * (double)d2);
          volatile float gg = factor * e;
          g[o++] = gg;
        }
    volatile float r[8];
    for (int j = 0; j < 8; ++j) r[j] = g[j];
    for (int j = 0; j < 8; ++j) r[j] = r[j] + g[8 + j];
    for (int j = 0; j < 8; ++j) r[j] = r[j] + g[16 + j];
    volatile float t01 = r[0] + r[1];
    volatile float t23 = r[2] + r[3];
    volatile float t45 = r[4] + r[5];
    volatile float t67 = r[6] + r[7];
    volatile float h0 = t01 + t23;
    volatile float h1 = t45 + t67;
    volatile float s = h0 + h1;
    s = s + g[24];
    s = s + g[25];
    s = s + g[26];
    for (int t = 0; t < 27; ++t) {
      volatile float w = g[t] / s;
      wt[t] = w;
    }
  }
  // 4 distinct weight values by d^2 symmetry: center/face/edge/corner.
  W4d wd = {(double)wt[13], (double)wt[12], (double)wt[9], (double)wt[0]};

  dim3 blk(256);
  // Big: runtime zslab=6 -> 4320 blocks (r13 best: 52 VGPR, occupancy 34%);
  // small: ZS=2 template -> 1440 blocks (r15 best); flow: 960 (r10 knee).
  dim3 gBig(WW / 8, HH / 6, 27);
  dim3 gSm(WW / 8, HH / 2, 3);
  int fblocks = NVOX / 4 / 256;    // 960

  // cv blur passes (pass 1 computes cv on the fly from src/tgt)
  blur4_kernel<true, 0><<<gBig, blk, 0, stream>>>(nullptr, src, tgt, cv1, 6, wd);
  blur4_kernel<false, 0><<<gBig, blk, 0, stream>>>(cv1, nullptr, nullptr, cv2, 6, wd);
  blur4_kernel<false, 0><<<gBig, blk, 0, stream>>>(cv2, nullptr, nullptr, cv1, 6, wd);
  // initial argmax flow (cv2 now dead -> fa/fb live there)
  flow4_kernel<0><<<fblocks, blk, 0, stream>>>(cv1, nullptr, 0.f, fa);
  blur4_kernel<false, 2><<<gSm, blk, 0, stream>>>(fa, nullptr, nullptr, fb, 2, wd);
  blur4_kernel<false, 2><<<gSm, blk, 0, stream>>>(fb, nullptr, nullptr, fa, 2, wd);
  blur4_kernel<false, 2><<<gSm, blk, 0, stream>>>(fa, nullptr, nullptr, fb, 2, wd);
  // six coupling iterations
  const float coefs[6] = {0.003f, 0.01f, 0.03f, 0.1f, 0.3f, 1.0f};
  for (int it = 0; it < 6; ++it) {
    flow4_kernel<1><<<fblocks, blk, 0, stream>>>(cv1, fb, coefs[it], fa);
    blur4_kernel<false, 2><<<gSm, blk, 0, stream>>>(fa, nullptr, nullptr, fb, 2, wd);
    blur4_kernel<false, 2><<<gSm, blk, 0, stream>>>(fb, nullptr, nullptr, fa, 2, wd);
    float* dst = (it == 5) ? out : fb;
    blur4_kernel<false, 2><<<gSm, blk, 0, stream>>>(fa, nullptr, nullptr, dst, 2, wd);
  }
}